// Round 3
// baseline (188.061 us; speedup 1.0000x reference)
//
#include <hip/hip_runtime.h>
#include <stdint.h>

#define MAX_TRIALS 50
#define MARGIN 1.0f
#define BLOCK 256

// ---------------- JAX threefry2x32, key = jax.random.key(42) = [0, 42] -----
// Verified bit-exact in round 1 (absmax 0.0). Do not touch.
__device__ __forceinline__ uint32_t rotl32(uint32_t x, uint32_t d) {
  return (x << d) | (x >> (32u - d));
}

__device__ __forceinline__ uint32_t threefry_0_42(uint32_t x0, uint32_t x1, int which) {
  const uint32_t k0 = 0u, k1 = 42u;
  const uint32_t k2 = k0 ^ k1 ^ 0x1BD11BDAu;
  const uint32_t ks[3] = {k0, k1, k2};
  const uint32_t rotA[4] = {13u, 15u, 26u, 6u};
  const uint32_t rotB[4] = {17u, 29u, 16u, 24u};
  x0 += ks[0];
  x1 += ks[1];
#pragma unroll
  for (int r = 0; r < 5; ++r) {
#pragma unroll
    for (int j = 0; j < 4; ++j) {
      uint32_t rot = (r & 1) ? rotB[j] : rotA[j];
      x0 += x1;
      x1 = rotl32(x1, rot);
      x1 ^= x0;
    }
    x0 += ks[(r + 1) % 3];
    x1 += ks[(r + 2) % 3] + (uint32_t)(r + 1);
  }
  return which ? x1 : x0;
}

// jax uniform element j of an (n,) draw, n = B*MAX_TRIALS:
// j < n/2 -> output 0 of threefry(j, j+n/2); else output 1 of (j-n/2, j)
__device__ __forceinline__ float sample_u(uint32_t j, uint32_t half) {
  uint32_t x0, x1;
  int which;
  if (j < half) { x0 = j; x1 = j + half; which = 0; }
  else          { x0 = j - half; x1 = j; which = 1; }
  uint32_t bits = threefry_0_42(x0, x1, which);
  return __uint_as_float((bits >> 9) | 0x3f800000u) - 1.0f;
}

// ---------------- K1: per-block count of label==0 --------------------------
__global__ void __launch_bounds__(BLOCK) count_kernel(const int* __restrict__ labels,
                                                      int* __restrict__ blockCounts, int B) {
  int gid = blockIdx.x * BLOCK + threadIdx.x;
  bool isNeg = (gid < B) && (labels[gid] == 0);
  unsigned long long m = __ballot(isNeg);
  __shared__ int wc[4];
  int lane = threadIdx.x & 63, wave = threadIdx.x >> 6;
  if (lane == 0) wc[wave] = __popcll(m);
  __syncthreads();
  if (threadIdx.x == 0) blockCounts[blockIdx.x] = wc[0] + wc[1] + wc[2] + wc[3];
}

// ---------------- K2: single-block PARALLEL exclusive scan -----------------
// Also zeroes total + done counter for the main kernel.
__global__ void __launch_bounds__(BLOCK) scan_kernel(const int* __restrict__ blockCounts,
                                                     int* __restrict__ blockOffsets,
                                                     int* __restrict__ counters,
                                                     float* __restrict__ total, int nblocks) {
  __shared__ int s_scan[BLOCK];
  int t = threadIdx.x;
  int per = (nblocks + BLOCK - 1) / BLOCK;  // 16 for nblocks=4096
  int base = t * per;
  int s = 0;
  for (int k = 0; k < per; ++k) {
    int i = base + k;
    if (i < nblocks) s += blockCounts[i];
  }
  s_scan[t] = s;
  __syncthreads();
  // Hillis-Steele inclusive scan over 256 partials
  for (int d = 1; d < BLOCK; d <<= 1) {
    int v = (t >= d) ? s_scan[t - d] : 0;
    __syncthreads();
    s_scan[t] += v;
    __syncthreads();
  }
  int excl = (t == 0) ? 0 : s_scan[t - 1];
  for (int k = 0; k < per; ++k) {
    int i = base + k;
    if (i < nblocks) {
      blockOffsets[i] = excl;
      excl += blockCounts[i];  // L2-hot re-read
    }
  }
  if (t == 0) {
    counters[0] = s_scan[BLOCK - 1];  // num_neg
    counters[1] = 0;                  // done counter for last-block finalize
    total[0] = 0.0f;                  // ws re-poisoned each call
  }
}

// ---------------- K3: stable compaction of negative SCORES -----------------
__global__ void __launch_bounds__(BLOCK) scatter_kernel(const float* __restrict__ scores,
                                                        const int* __restrict__ labels,
                                                        const int* __restrict__ blockOffsets,
                                                        float* __restrict__ negScores, int B) {
  int gid = blockIdx.x * BLOCK + threadIdx.x;
  bool isNeg = (gid < B) && (labels[gid] == 0);
  float sc = isNeg ? scores[gid] : 0.0f;
  unsigned long long m = __ballot(isNeg);
  int lane = threadIdx.x & 63, wave = threadIdx.x >> 6;
  __shared__ int wc[4];
  if (lane == 0) wc[wave] = __popcll(m);
  __syncthreads();
  int off = 0;
  for (int w = 0; w < wave; ++w) off += wc[w];
  if (isNeg)
    negScores[blockOffsets[blockIdx.x] + off + __popcll(m & ((1ULL << lane) - 1ULL))] = sc;
}

// ---------------- K4: two-phase sampling + finalize ------------------------
// Phase A: 2 speculative independent trials per positive (uniform, parallel
// gathers). Survivors -> LDS queue. Phase B: one wave per survivor, trials
// 2..49 lane-parallel, ballot+ffs finds the first violation.
__global__ void __launch_bounds__(BLOCK) warp_main(const float* __restrict__ scores,
                                                   const int* __restrict__ labels,
                                                   const float* __restrict__ negScores,
                                                   const int* __restrict__ counters,
                                                   float* __restrict__ total,
                                                   float* __restrict__ out, int B) {
  __shared__ float H[MAX_TRIALS + 1];
  __shared__ int s_qe[BLOCK];
  __shared__ float s_qs[BLOCK];
  __shared__ int s_qn;
  __shared__ float s_bsum[4];

  const int tid = threadIdx.x;
  const int lane = tid & 63;
  const int wave = tid >> 6;

  if (tid == 0) {
    float a = 0.0f;  // fp32 sequential cumsum == jnp.cumsum of 1/k
    for (int k = 1; k <= MAX_TRIALS; ++k) { a += 1.0f / (float)k; H[k] = a; }
    s_qn = 0;
  }
  __syncthreads();

  const int num_neg = counters[0];
  const float fneg = (float)num_neg;
  const uint32_t half = (uint32_t)(((unsigned long long)B * MAX_TRIALS) >> 1);
  const int e = blockIdx.x * BLOCK + tid;

  float acc = 0.0f;
  bool survive = false;
  float s = 0.0f;

  if (e < B && num_neg > 0 && labels[e] == 1) {
    s = scores[e];
    uint32_t jb = (uint32_t)e * (uint32_t)MAX_TRIALS;
    // both trials computed & gathered speculatively -> one memory latency
    float u0 = sample_u(jb, half);
    float u1 = sample_u(jb + 1u, half);
    int i0 = (int)(u0 * fneg);  // trunc toward zero == astype(int32)
    int i1 = (int)(u1 * fneg);
    if (i0 > num_neg - 1) i0 = num_neg - 1;
    if (i1 > num_neg - 1) i1 = num_neg - 1;
    float n0 = negScores[i0];
    float n1 = negScores[i1];
    if (n0 + MARGIN > s) {           // trials=0 -> rank=50
      float h = MARGIN - (s - n0);
      if (h < 0.0f) h = 0.0f;
      acc = H[50] * h;
    } else if (n1 + MARGIN > s) {    // trials=1 -> rank=25
      float h = MARGIN - (s - n1);
      if (h < 0.0f) h = 0.0f;
      acc = H[25] * h;
    } else {
      survive = true;
    }
  }

  // enqueue survivors into block-local LDS queue (order irrelevant for sum)
  unsigned long long m = __ballot(survive);
  int c = __popcll(m);
  if (c) {
    int wbase = 0;
    if (lane == 0) wbase = atomicAdd(&s_qn, c);  // LDS atomic
    wbase = __shfl(wbase, 0, 64);
    if (survive) {
      int p = wbase + __popcll(m & ((1ULL << lane) - 1ULL));
      s_qe[p] = e;
      s_qs[p] = s;
    }
  }
  __syncthreads();

  // phase B: one wave per survivor, lanes = trials 2..49
  const int qn = s_qn;
  for (int q = wave; q < qn; q += 4) {
    float sq = s_qs[q];
    int eq = s_qe[q];
    int t = 2 + lane;
    bool viol = false;
    float neg = 0.0f;
    if (t < MAX_TRIALS) {
      float u = sample_u((uint32_t)eq * (uint32_t)MAX_TRIALS + (uint32_t)t, half);
      int idx = (int)(u * fneg);
      if (idx > num_neg - 1) idx = num_neg - 1;
      neg = negScores[idx];
      viol = (neg + MARGIN > sq);
    }
    unsigned long long vm = __ballot(viol);
    if (vm) {
      int f = __ffsll(vm) - 1;  // lowest lane == first violating trial
      if (lane == f) {
        int trials = 2 + f;
        int rank = MAX_TRIALS / (trials + 1);
        if (rank < 1) rank = 1;
        float h = MARGIN - (sq - neg);
        if (h < 0.0f) h = 0.0f;
        acc += H[rank] * h;
      }
    }
    // vm == 0 -> no violation in 50 trials -> contributes 0 (matches ref)
  }

  // block reduce -> one global atomic per block
  float v = acc;
#pragma unroll
  for (int off = 32; off > 0; off >>= 1) v += __shfl_down(v, off, 64);
  if (lane == 0) s_bsum[wave] = v;
  __syncthreads();
  if (tid == 0) {
    atomicAdd(total, s_bsum[0] + s_bsum[1] + s_bsum[2] + s_bsum[3]);
    __threadfence();                               // release my total-add
    int old = atomicAdd((int*)&counters[1], 1);    // arrival counter (zeroed by K2)
    if (old == (int)gridDim.x - 1) {               // I'm the last block
      __threadfence();                             // acquire others' total-adds
      float tt = atomicAdd(total, 0.0f);           // coherent read (L1 bypass)
      int np = B - num_neg;
      float r = 0.0f;
      if (np > 0 && num_neg > 0) r = tt / (float)np;
      out[0] = r;
    }
  }
}

extern "C" void kernel_launch(void* const* d_in, const int* in_sizes, int n_in,
                              void* d_out, int out_size, void* d_ws, size_t ws_size,
                              hipStream_t stream) {
  const float* scores = (const float*)d_in[0];
  const int* labels = (const int*)d_in[1];
  int B = in_sizes[0];
  int nblocks = (B + BLOCK - 1) / BLOCK;

  // workspace layout (same footprint class as round 1, ~4.2 MB)
  char* ws = (char*)d_ws;
  int* counters = (int*)ws;                    // [0]=num_neg [1]=done counter
  float* total = (float*)(ws + 16);            // loss accumulator
  int* blockCounts = (int*)(ws + 64);          // nblocks ints
  int* blockOffsets = blockCounts + nblocks;   // nblocks ints
  float* negScores = (float*)(blockOffsets + nblocks);  // B floats (first num_neg used)

  count_kernel<<<nblocks, BLOCK, 0, stream>>>(labels, blockCounts, B);
  scan_kernel<<<1, BLOCK, 0, stream>>>(blockCounts, blockOffsets, counters, total, nblocks);
  scatter_kernel<<<nblocks, BLOCK, 0, stream>>>(scores, labels, blockOffsets, negScores, B);
  warp_main<<<nblocks, BLOCK, 0, stream>>>(scores, labels, negScores, counters, total,
                                           (float*)d_out, B);
}

// Round 4
// 98.383 us; speedup vs baseline: 1.9115x; 1.9115x over previous
//
#include <hip/hip_runtime.h>
#include <stdint.h>

#define MAX_TRIALS 50
#define MARGIN 1.0f
#define BLOCK 256

// ---------------- JAX threefry2x32, key = jax.random.key(42) = [0, 42] -----
// Verified bit-exact in rounds 1/3 (absmax 0.0). Do not touch.
__device__ __forceinline__ uint32_t rotl32(uint32_t x, uint32_t d) {
  return (x << d) | (x >> (32u - d));
}

__device__ __forceinline__ uint32_t threefry_0_42(uint32_t x0, uint32_t x1, int which) {
  const uint32_t k0 = 0u, k1 = 42u;
  const uint32_t k2 = k0 ^ k1 ^ 0x1BD11BDAu;
  const uint32_t ks[3] = {k0, k1, k2};
  const uint32_t rotA[4] = {13u, 15u, 26u, 6u};
  const uint32_t rotB[4] = {17u, 29u, 16u, 24u};
  x0 += ks[0];
  x1 += ks[1];
#pragma unroll
  for (int r = 0; r < 5; ++r) {
#pragma unroll
    for (int j = 0; j < 4; ++j) {
      uint32_t rot = (r & 1) ? rotB[j] : rotA[j];
      x0 += x1;
      x1 = rotl32(x1, rot);
      x1 ^= x0;
    }
    x0 += ks[(r + 1) % 3];
    x1 += ks[(r + 2) % 3] + (uint32_t)(r + 1);
  }
  return which ? x1 : x0;
}

// jax uniform element j of an (n,) draw, n = B*MAX_TRIALS:
// j < n/2 -> output 0 of threefry(j, j+n/2); else output 1 of (j-n/2, j)
__device__ __forceinline__ float sample_u(uint32_t j, uint32_t half) {
  uint32_t x0, x1;
  int which;
  if (j < half) { x0 = j; x1 = j + half; which = 0; }
  else          { x0 = j - half; x1 = j; which = 1; }
  uint32_t bits = threefry_0_42(x0, x1, which);
  return __uint_as_float((bits >> 9) | 0x3f800000u) - 1.0f;
}

// ---------------- K1: per-block count of label==0 --------------------------
__global__ void __launch_bounds__(BLOCK) count_kernel(const int* __restrict__ labels,
                                                      int* __restrict__ blockCounts, int B) {
  int gid = blockIdx.x * BLOCK + threadIdx.x;
  bool isNeg = (gid < B) && (labels[gid] == 0);
  unsigned long long m = __ballot(isNeg);
  __shared__ int wc[4];
  int lane = threadIdx.x & 63, wave = threadIdx.x >> 6;
  if (lane == 0) wc[wave] = __popcll(m);
  __syncthreads();
  if (threadIdx.x == 0) blockCounts[blockIdx.x] = wc[0] + wc[1] + wc[2] + wc[3];
}

// ---------------- K2: single-block PARALLEL exclusive scan -----------------
__global__ void __launch_bounds__(BLOCK) scan_kernel(const int* __restrict__ blockCounts,
                                                     int* __restrict__ blockOffsets,
                                                     int* __restrict__ counters, int nblocks) {
  __shared__ int s_scan[BLOCK];
  int t = threadIdx.x;
  int per = (nblocks + BLOCK - 1) / BLOCK;  // 16 for nblocks=4096
  int base = t * per;
  int s = 0;
  for (int k = 0; k < per; ++k) {
    int i = base + k;
    if (i < nblocks) s += blockCounts[i];
  }
  s_scan[t] = s;
  __syncthreads();
  // Hillis-Steele inclusive scan over 256 partials
  for (int d = 1; d < BLOCK; d <<= 1) {
    int v = (t >= d) ? s_scan[t - d] : 0;
    __syncthreads();
    s_scan[t] += v;
    __syncthreads();
  }
  int excl = (t == 0) ? 0 : s_scan[t - 1];
  for (int k = 0; k < per; ++k) {
    int i = base + k;
    if (i < nblocks) {
      blockOffsets[i] = excl;
      excl += blockCounts[i];  // L2-hot re-read
    }
  }
  if (t == 0) counters[0] = s_scan[BLOCK - 1];  // num_neg
}

// ---------------- K3: stable compaction of negative SCORES -----------------
__global__ void __launch_bounds__(BLOCK) scatter_kernel(const float* __restrict__ scores,
                                                        const int* __restrict__ labels,
                                                        const int* __restrict__ blockOffsets,
                                                        float* __restrict__ negScores, int B) {
  int gid = blockIdx.x * BLOCK + threadIdx.x;
  bool isNeg = (gid < B) && (labels[gid] == 0);
  float sc = isNeg ? scores[gid] : 0.0f;
  unsigned long long m = __ballot(isNeg);
  int lane = threadIdx.x & 63, wave = threadIdx.x >> 6;
  __shared__ int wc[4];
  if (lane == 0) wc[wave] = __popcll(m);
  __syncthreads();
  int off = 0;
  for (int w = 0; w < wave; ++w) off += wc[w];
  if (isNeg)
    negScores[blockOffsets[blockIdx.x] + off + __popcll(m & ((1ULL << lane) - 1ULL))] = sc;
}

// ---------------- K4: two-phase sampling, NO same-address atomics ----------
// Phase A: 2 speculative independent trials per positive (uniform control
// flow, parallel gathers). Survivors -> LDS queue. Phase B: one wave per
// survivor, trials 2..49 lane-parallel, ballot+ffs finds first violation.
// Block partial sum goes to partial[blockIdx.x] -- a plain store. The round-3
// atomicAdd(total)+arrival-counter pattern serialized 8192 same-address
// device atomics at ~15ns each = the whole 125us. Never again.
__global__ void __launch_bounds__(BLOCK) warp_main(const float* __restrict__ scores,
                                                   const int* __restrict__ labels,
                                                   const float* __restrict__ negScores,
                                                   const int* __restrict__ counters,
                                                   float* __restrict__ partial, int B) {
  __shared__ float H[MAX_TRIALS + 1];
  __shared__ int s_qe[BLOCK];
  __shared__ float s_qs[BLOCK];
  __shared__ int s_qn;
  __shared__ float s_bsum[4];

  const int tid = threadIdx.x;
  const int lane = tid & 63;
  const int wave = tid >> 6;

  if (tid == 0) {
    float a = 0.0f;  // fp32 sequential cumsum == jnp.cumsum of 1/k
    for (int k = 1; k <= MAX_TRIALS; ++k) { a += 1.0f / (float)k; H[k] = a; }
    s_qn = 0;
  }
  __syncthreads();

  const int num_neg = counters[0];
  const float fneg = (float)num_neg;
  const uint32_t half = (uint32_t)(((unsigned long long)B * MAX_TRIALS) >> 1);
  const int e = blockIdx.x * BLOCK + tid;

  float acc = 0.0f;
  bool survive = false;
  float s = 0.0f;

  if (e < B && num_neg > 0 && labels[e] == 1) {
    s = scores[e];
    uint32_t jb = (uint32_t)e * (uint32_t)MAX_TRIALS;
    // both trials computed & gathered speculatively -> one memory latency
    float u0 = sample_u(jb, half);
    float u1 = sample_u(jb + 1u, half);
    int i0 = (int)(u0 * fneg);  // trunc toward zero == astype(int32)
    int i1 = (int)(u1 * fneg);
    if (i0 > num_neg - 1) i0 = num_neg - 1;
    if (i1 > num_neg - 1) i1 = num_neg - 1;
    float n0 = negScores[i0];
    float n1 = negScores[i1];
    if (n0 + MARGIN > s) {           // trials=0 -> rank=50
      float h = MARGIN - (s - n0);
      if (h < 0.0f) h = 0.0f;
      acc = H[50] * h;
    } else if (n1 + MARGIN > s) {    // trials=1 -> rank=25
      float h = MARGIN - (s - n1);
      if (h < 0.0f) h = 0.0f;
      acc = H[25] * h;
    } else {
      survive = true;
    }
  }

  // enqueue survivors into block-local LDS queue (order irrelevant for sum)
  unsigned long long m = __ballot(survive);
  int c = __popcll(m);
  if (c) {
    int wbase = 0;
    if (lane == 0) wbase = atomicAdd(&s_qn, c);  // LDS atomic: cheap, block-local
    wbase = __shfl(wbase, 0, 64);
    if (survive) {
      int p = wbase + __popcll(m & ((1ULL << lane) - 1ULL));
      s_qe[p] = e;
      s_qs[p] = s;
    }
  }
  __syncthreads();

  // phase B: one wave per survivor, lanes = trials 2..49
  const int qn = s_qn;
  for (int q = wave; q < qn; q += 4) {
    float sq = s_qs[q];
    int eq = s_qe[q];
    int t = 2 + lane;
    bool viol = false;
    float neg = 0.0f;
    if (t < MAX_TRIALS) {
      float u = sample_u((uint32_t)eq * (uint32_t)MAX_TRIALS + (uint32_t)t, half);
      int idx = (int)(u * fneg);
      if (idx > num_neg - 1) idx = num_neg - 1;
      neg = negScores[idx];
      viol = (neg + MARGIN > sq);
    }
    unsigned long long vm = __ballot(viol);
    if (vm) {
      int f = __ffsll(vm) - 1;  // lowest lane == first violating trial
      if (lane == f) {
        int trials = 2 + f;
        int rank = MAX_TRIALS / (trials + 1);
        if (rank < 1) rank = 1;
        float h = MARGIN - (sq - neg);
        if (h < 0.0f) h = 0.0f;
        acc += H[rank] * h;
      }
    }
    // vm == 0 -> no violation in 50 trials -> contributes 0 (matches ref)
  }

  // block reduce -> ONE plain store per block, distinct addresses
  float v = acc;
#pragma unroll
  for (int off = 32; off > 0; off >>= 1) v += __shfl_down(v, off, 64);
  if (lane == 0) s_bsum[wave] = v;
  __syncthreads();
  if (tid == 0) partial[blockIdx.x] = s_bsum[0] + s_bsum[1] + s_bsum[2] + s_bsum[3];
}

// ---------------- K5: reduce 4096 partials + finalize ----------------------
__global__ void __launch_bounds__(BLOCK) finalize_kernel(const float* __restrict__ partial,
                                                         int nparts,
                                                         const int* __restrict__ counters,
                                                         float* __restrict__ out, int B) {
  __shared__ float s_bsum[4];
  float v = 0.0f;
  for (int i = threadIdx.x; i < nparts; i += BLOCK) v += partial[i];
#pragma unroll
  for (int off = 32; off > 0; off >>= 1) v += __shfl_down(v, off, 64);
  int lane = threadIdx.x & 63, wave = threadIdx.x >> 6;
  if (lane == 0) s_bsum[wave] = v;
  __syncthreads();
  if (threadIdx.x == 0) {
    int num_neg = counters[0];
    int np = B - num_neg;
    float tt = s_bsum[0] + s_bsum[1] + s_bsum[2] + s_bsum[3];
    float r = 0.0f;
    if (np > 0 && num_neg > 0) r = tt / (float)np;
    out[0] = r;
  }
}

extern "C" void kernel_launch(void* const* d_in, const int* in_sizes, int n_in,
                              void* d_out, int out_size, void* d_ws, size_t ws_size,
                              hipStream_t stream) {
  const float* scores = (const float*)d_in[0];
  const int* labels = (const int*)d_in[1];
  int B = in_sizes[0];
  int nblocks = (B + BLOCK - 1) / BLOCK;

  // workspace layout (~4.25 MB for B=1M)
  char* ws = (char*)d_ws;
  int* counters = (int*)ws;                    // [0]=num_neg
  int* blockCounts = (int*)(ws + 64);          // nblocks ints
  int* blockOffsets = blockCounts + nblocks;   // nblocks ints
  float* partial = (float*)(blockOffsets + nblocks);  // nblocks floats
  float* negScores = partial + nblocks;        // B floats (first num_neg used)

  count_kernel<<<nblocks, BLOCK, 0, stream>>>(labels, blockCounts, B);
  scan_kernel<<<1, BLOCK, 0, stream>>>(blockCounts, blockOffsets, counters, nblocks);
  scatter_kernel<<<nblocks, BLOCK, 0, stream>>>(scores, labels, blockOffsets, negScores, B);
  warp_main<<<nblocks, BLOCK, 0, stream>>>(scores, labels, negScores, counters, partial, B);
  finalize_kernel<<<1, BLOCK, 0, stream>>>(partial, nblocks, counters, (float*)d_out, B);
}